// Round 1
// baseline (2045.423 us; speedup 1.0000x reference)
//
#include <hip/hip_runtime.h>

// LIF neuron layer, fused: currents GEMM (fp32 VALU) + sequential threshold scan.
// B=128, I=2048, O=2048, T=100.
// Grid: 128 b * 8 o-chunks (256 o each). Block: 256 thr = 4 t-quarters x 64 lanes.
// Each thread: 4 consecutive o (lane*4+j) x 25 t (tq*25+tt), acc in float4[25].

#define BB 128
#define II 2048
#define OO 2048
#define TT_ 100
#define TI 32      // i-tile
#define TO 256     // o per block

__launch_bounds__(256, 3)
__global__ void lif_fused_kernel(const float* __restrict__ spike,
                                 const float* __restrict__ weight,
                                 float* __restrict__ out) {
    __shared__ float Wlds[TI][TO];     // 32 KB
    __shared__ float Slds[TI][128];    // 16 KB: 4 tq segments x 32 slots (25 used)
    __shared__ float m_buf[TO];        // 1 KB membrane handoff

    const int tid  = threadIdx.x;
    const int lane = tid & 63;
    const int tq   = tid >> 6;         // wave index == t-quarter
    const int b    = blockIdx.x >> 3;
    const int oc   = blockIdx.x & 7;
    const int o0   = oc * TO;

    float4 acc[25];
#pragma unroll
    for (int t = 0; t < 25; ++t) acc[t] = make_float4(0.f, 0.f, 0.f, 0.f);

    const float4* Wf4 = (const float4*)weight;   // [II][OO/4]

    for (int it = 0; it < II / TI; ++it) {
        const int i0 = it * TI;
        __syncthreads();   // previous tile fully consumed

        // ---- stage W[i0:i0+32][o0:o0+256] -> Wlds (float4, fully coalesced)
#pragma unroll
        for (int k = 0; k < 8; ++k) {
            int flat4 = k * 256 + tid;           // 0..2047
            int i_l = flat4 >> 6;                // /64
            int o4  = flat4 & 63;
            float4 v = Wf4[(i0 + i_l) * (OO / 4) + (o0 >> 2) + o4];
            ((float4*)Wlds)[i_l * (TO / 4) + o4] = v;
        }
        // ---- stage spike[b][i0:i0+32][0:100] -> Slds with tq-segment padding
#pragma unroll
        for (int k = 0; k < 13; ++k) {
            int flat = k * 256 + tid;            // 0..3327
            if (flat < TI * TT_) {
                int i_l = flat / TT_;
                int t   = flat - i_l * TT_;
                int q   = t / 25;
                int tt  = t - q * 25;
                Slds[i_l][q * 32 + tt] =
                    spike[(b * II + i0 + i_l) * TT_ + t];
            }
        }
        __syncthreads();

        // ---- compute: 32 i x (4 o x 25 t) FMAs
        for (int i_l = 0; i_l < TI; ++i_l) {
            float4 w = ((const float4*)Wlds)[i_l * (TO / 4) + lane];
            const float* srow = &Slds[i_l][tq * 32];   // 16B-aligned (128B offset)
#pragma unroll
            for (int v = 0; v < 6; ++v) {
                float4 sv = ((const float4*)srow)[v];
                acc[v*4+0].x = fmaf(w.x, sv.x, acc[v*4+0].x);
                acc[v*4+0].y = fmaf(w.y, sv.x, acc[v*4+0].y);
                acc[v*4+0].z = fmaf(w.z, sv.x, acc[v*4+0].z);
                acc[v*4+0].w = fmaf(w.w, sv.x, acc[v*4+0].w);
                acc[v*4+1].x = fmaf(w.x, sv.y, acc[v*4+1].x);
                acc[v*4+1].y = fmaf(w.y, sv.y, acc[v*4+1].y);
                acc[v*4+1].z = fmaf(w.z, sv.y, acc[v*4+1].z);
                acc[v*4+1].w = fmaf(w.w, sv.y, acc[v*4+1].w);
                acc[v*4+2].x = fmaf(w.x, sv.z, acc[v*4+2].x);
                acc[v*4+2].y = fmaf(w.y, sv.z, acc[v*4+2].y);
                acc[v*4+2].z = fmaf(w.z, sv.z, acc[v*4+2].z);
                acc[v*4+2].w = fmaf(w.w, sv.z, acc[v*4+2].w);
                acc[v*4+3].x = fmaf(w.x, sv.w, acc[v*4+3].x);
                acc[v*4+3].y = fmaf(w.y, sv.w, acc[v*4+3].y);
                acc[v*4+3].z = fmaf(w.z, sv.w, acc[v*4+3].z);
                acc[v*4+3].w = fmaf(w.w, sv.w, acc[v*4+3].w);
            }
            float s24 = srow[24];
            acc[24].x = fmaf(w.x, s24, acc[24].x);
            acc[24].y = fmaf(w.y, s24, acc[24].y);
            acc[24].z = fmaf(w.z, s24, acc[24].z);
            acc[24].w = fmaf(w.w, s24, acc[24].w);
        }
    }

    // ---- sequential LIF scan: 4 rounds (t-quarters), membrane handoff via LDS.
    __syncthreads();
    for (int r = 0; r < 4; ++r) {
        if (tq == r) {
#pragma unroll
            for (int j = 0; j < 4; ++j) {
                const int ol = lane * 4 + j;
                const int o  = o0 + ol;
                float m = (r == 0) ? 0.0f : m_buf[ol];
                float* orow = out + (b * OO + o) * TT_ + r * 25;
#pragma unroll
                for (int t = 0; t < 25; ++t) {
                    float c = (j == 0) ? acc[t].x
                            : (j == 1) ? acc[t].y
                            : (j == 2) ? acc[t].z
                            :            acc[t].w;
                    m += c;
                    bool f = (m > 1.0f);         // strict >, matches reference
                    orow[t] = f ? 1.0f : 0.0f;
                    m = f ? 0.0f : m;            // reset voltage = 0
                }
                m_buf[ol] = m;
            }
        }
        __syncthreads();
    }
}

extern "C" void kernel_launch(void* const* d_in, const int* in_sizes, int n_in,
                              void* d_out, int out_size, void* d_ws, size_t ws_size,
                              hipStream_t stream) {
    const float* spike  = (const float*)d_in[0];   // [128][2048][100]
    const float* weight = (const float*)d_in[1];   // [2048][2048]
    float* out = (float*)d_out;                    // [128][2048][100]

    dim3 grid(BB * (OO / TO));   // 1024 blocks
    dim3 block(256);
    lif_fused_kernel<<<grid, block, 0, stream>>>(spike, weight, out);
}